// Round 8
// baseline (248.562 us; speedup 1.0000x reference)
//
#include <hip/hip_runtime.h>
#include <cstdint>
#include <cstddef>

typedef unsigned short u16;
typedef __attribute__((ext_vector_type(8))) short bf16x8;   // 8 bf16 = 4 VGPR
typedef __attribute__((ext_vector_type(4))) short bf16x4;   // 4 bf16 = 2 VGPR
typedef __attribute__((ext_vector_type(4))) float f32x4;
typedef __attribute__((ext_vector_type(16))) float f32x16;
typedef __attribute__((ext_vector_type(4))) unsigned short u16x4;

#define NB 16
#define CD 512
#define SD 1024
#define NH 8
#define HD 64

// 0.125 (1/sqrt(64)) * log2(e): folded into Q so softmax runs in log2 domain
#define QSCL 0.18033688011112042f

__device__ __forceinline__ u16 f2bf(float f) {          // round-to-nearest-even
    unsigned u = __float_as_uint(f);
    u += 0x7FFF + ((u >> 16) & 1);
    return (u16)(u >> 16);
}
__device__ __forceinline__ unsigned cvt_pk(float lo, float hi) {
    unsigned r;
    asm("v_cvt_pk_bf16_f32 %0, %1, %2" : "=v"(r) : "v"(lo), "v"(hi));
    return r;
}
__device__ __forceinline__ float exp2v(float x) {       // 2^x, single v_exp_f32
    float r;
    asm("v_exp_f32 %0, %1" : "=v"(r) : "v"(x));
    return r;
}
__device__ __forceinline__ void gload16(const void* g, void* l) {
    __builtin_amdgcn_global_load_lds(
        (const __attribute__((address_space(1))) void*)g,
        (__attribute__((address_space(3))) void*)l, 16, 0, 0);
}

// ---------------------------------------------------------------------------
// fp32 -> bf16 weight convert (both weight tensors in one launch)
// ---------------------------------------------------------------------------
__global__ __launch_bounds__(256) void cvt2_kernel(
    const float* __restrict__ s0, u16* __restrict__ d0,
    const float* __restrict__ s1, u16* __restrict__ d1)
{
    const int bid = blockIdx.x;
    const float* s;
    u16* d;
    int i;
    if (bid < 768) { s = s0; d = d0; i = (bid * 256 + threadIdx.x) * 4; }
    else           { s = s1; d = d1; i = ((bid - 768) * 256 + threadIdx.x) * 4; }
    float4 v = *reinterpret_cast<const float4*>(s + i);
    u16x4 o = { f2bf(v.x), f2bf(v.y), f2bf(v.z), f2bf(v.w) };
    *reinterpret_cast<u16x4*>(d + i) = o;
}

// ---------------------------------------------------------------------------
// GroupNorm: x [n][c][s] fp32 -> h [n][s][c] bf16
// ---------------------------------------------------------------------------
__global__ __launch_bounds__(256) void gn_kernel(
    const float* __restrict__ x, const float* __restrict__ w,
    const float* __restrict__ b, u16* __restrict__ h)
{
    const int n = blockIdx.x >> 5, g = blockIdx.x & 31;
    const size_t base = ((size_t)n * CD + g * 16) * SD;
    const float4* xp = reinterpret_cast<const float4*>(x + base);

    float4 vals[16];
    float sum = 0.f, ss = 0.f;
#pragma unroll
    for (int i = 0; i < 16; ++i) {
        float4 v = xp[threadIdx.x + (i << 8)];
        vals[i] = v;
        sum += v.x + v.y + v.z + v.w;
        ss  += v.x*v.x + v.y*v.y + v.z*v.z + v.w*v.w;
    }
#pragma unroll
    for (int off = 32; off > 0; off >>= 1) {
        sum += __shfl_down(sum, off);
        ss  += __shfl_down(ss,  off);
    }
    __shared__ float rs[4], rq[4];
    const int wid = threadIdx.x >> 6, lane = threadIdx.x & 63;
    if (lane == 0) { rs[wid] = sum; rq[wid] = ss; }
    __syncthreads();
    const float tsum = rs[0] + rs[1] + rs[2] + rs[3];
    const float tss  = rq[0] + rq[1] + rq[2] + rq[3];
    const float mean = tsum * (1.0f / 16384.0f);
    const float var  = tss * (1.0f / 16384.0f) - mean * mean;
    const float inv  = rsqrtf(var + 1e-5f);

    u16* hp = h + ((size_t)n * SD + 4 * threadIdx.x) * CD + g * 16;
#pragma unroll
    for (int i = 0; i < 16; ++i) {
        const float A  = inv * w[g * 16 + i];
        const float Bc = b[g * 16 + i] - mean * A;
        float4 v = vals[i];
        hp[i]          = f2bf(v.x * A + Bc);
        hp[CD + i]     = f2bf(v.y * A + Bc);
        hp[2 * CD + i] = f2bf(v.z * A + Bc);
        hp[3 * CD + i] = f2bf(v.w * A + Bc);
    }
}

// ---------------------------------------------------------------------------
// MFMA GEMM, K = 512. Tile 128x128, BK=64, 4 waves, 16x16x32 MFMA,
// XOR-granule swizzled LDS via global_load_lds. Template MODE = branch-free
// inner loop (R4 lesson). MODE 0: m<512 scaled by QSCL -> qk; m>=1024 -> V
// with HALF-SWAPPED granules: s^4 for c-rows with bit3 set, so attn's b64
// V-reads cover all 32 banks (R7 bank-conflict fix). MODE 1: D^T + resid.
// ---------------------------------------------------------------------------
template<int MODE>
__global__ __launch_bounds__(256) void mfma_gemm(
    const u16* __restrict__ Wb, const u16* __restrict__ act,
    const float* __restrict__ bias, const float* __restrict__ resid,
    void* __restrict__ outp, u16* __restrict__ vtout, int M)
{
    const int nb = blockIdx.z, m0 = blockIdx.y * 128, s0 = blockIdx.x * 128;
    __shared__ u16 Al[128 * 64];
    __shared__ u16 Bl[128 * 64];
    const int tid = threadIdx.x, wv = tid >> 6, ln = tid & 63;
    const int wm = wv >> 1, wn = wv & 1, lr = ln & 15, lg = ln >> 4;

    const f32x4 zero = {0.f, 0.f, 0.f, 0.f};
    f32x4 acc[4][4];
#pragma unroll
    for (int i = 0; i < 4; ++i)
#pragma unroll
        for (int j = 0; j < 4; ++j) acc[i][j] = zero;

    const u16* Ab = Wb + (size_t)m0 * CD;
    const u16* Bb = act + ((size_t)nb * SD + s0) * CD;

    for (int k0 = 0; k0 < CD; k0 += 64) {
        __syncthreads();
#pragma unroll
        for (int r = 0; r < 4; ++r) {
            const int gi = (r * 4 + wv) * 64 + ln;
            const int row = gi >> 3, gc = gi & 7;
            const int sg = ((gc ^ (row & 7)) * 8);
            gload16(Ab + (size_t)row * CD + k0 + sg, Al + gi * 8);
            gload16(Bb + (size_t)row * CD + k0 + sg, Bl + gi * 8);
        }
        __syncthreads();

#pragma unroll
        for (int kc = 0; kc < 2; ++kc) {
            bf16x8 af[4], bfr[4];
#pragma unroll
            for (int mi = 0; mi < 4; ++mi) {
                const int row = wm * 64 + mi * 16 + lr;
                af[mi] = *reinterpret_cast<const bf16x8*>(
                    Al + row * 64 + (((kc * 4 + lg) ^ (row & 7)) * 8));
            }
#pragma unroll
            for (int nj = 0; nj < 4; ++nj) {
                const int row = wn * 64 + nj * 16 + lr;
                bfr[nj] = *reinterpret_cast<const bf16x8*>(
                    Bl + row * 64 + (((kc * 4 + lg) ^ (row & 7)) * 8));
            }
#pragma unroll
            for (int mi = 0; mi < 4; ++mi)
#pragma unroll
                for (int nj = 0; nj < 4; ++nj) {
                    if (MODE == 0)
                        acc[mi][nj] = __builtin_amdgcn_mfma_f32_16x16x32_bf16(
                            af[mi], bfr[nj], acc[mi][nj], 0, 0, 0);
                    else   // D^T: A = act rows (s), B = weight rows (m)
                        acc[mi][nj] = __builtin_amdgcn_mfma_f32_16x16x32_bf16(
                            bfr[mi], af[nj], acc[mi][nj], 0, 0, 0);
                }
        }
    }

    if (MODE == 0) {
        if (m0 < 1024) {                                     // Q|K -> qk[n][s][1024]
            u16* o = (u16*)outp;
            const float sc = (m0 < 512) ? QSCL : 1.0f;       // whole block uniform
#pragma unroll
            for (int mi = 0; mi < 4; ++mi) {
                const int mb = m0 + wm * 64 + mi * 16 + lg * 4;
#pragma unroll
                for (int nj = 0; nj < 4; ++nj) {
                    const int s = s0 + wn * 64 + nj * 16 + lr;
                    u16x4 pack;
#pragma unroll
                    for (int r = 0; r < 4; ++r)
                        pack[r] = f2bf((acc[mi][nj][r] + bias[mb + r]) * sc);
                    *reinterpret_cast<u16x4*>(o + ((size_t)nb * SD + s) * 1024 + mb) = pack;
                }
            }
        } else {                                             // V -> vt[(n*512+c)][s]
            // half-swap: c-rows with bit3 set store s^4 (bank-conflict fix)
            const int sswap = (lg >= 2) ? 4 : 0;
#pragma unroll
            for (int mi = 0; mi < 4; ++mi)
#pragma unroll
                for (int r = 0; r < 4; ++r) {
                    const int m = m0 + wm * 64 + mi * 16 + lg * 4 + r;
                    const float bi = bias[m];
#pragma unroll
                    for (int nj = 0; nj < 4; ++nj) {
                        const int s = (s0 + wn * 64 + nj * 16 + lr) ^ sswap;
                        vtout[((size_t)nb * 512 + (m - 1024)) * SD + s] = f2bf(acc[mi][nj][r] + bi);
                    }
                }
        }
    } else {
        // D^T epilogue: acc[i][j] rows = s (i-frags), cols = m (j-frags)
        float* o = (float*)outp;
#pragma unroll
        for (int i = 0; i < 4; ++i)
#pragma unroll
            for (int j = 0; j < 4; ++j) {
                const int m = m0 + wm * 64 + j * 16 + lr;
                const int s = s0 + wn * 64 + i * 16 + lg * 4;
                const float bi = bias[m];
                const size_t idx = ((size_t)nb * M + m) * SD + s;
                float4 r4 = *reinterpret_cast<const float4*>(resid + idx);
                float4 v;
                v.x = acc[i][j][0] + bi + r4.x;
                v.y = acc[i][j][1] + bi + r4.y;
                v.z = acc[i][j][2] + bi + r4.z;
                v.w = acc[i][j][3] + bi + r4.w;
                *reinterpret_cast<float4*>(o + idx) = v;
            }
    }
}

// ---------------------------------------------------------------------------
// Flash attention, 32x32x16 bf16 MFMA, swapped QK^T, P in-register, log2-
// domain softmax, defer-max. R7: 4-wave blocks (QBLK=128, grid 1024 -> 4
// blocks/CU); grid axes swapped so a head's q-blocks share one XCD (flat%8);
// V b64 reads use half-key hi^(lq>>3) matching gemm's half-swapped store
// (all-32-bank coverage); tree max/sum; exp2 in place over st (VGPR diet).
// ---------------------------------------------------------------------------
__global__ __launch_bounds__(256) void attn_mfma(
    const u16* __restrict__ qk, const u16* __restrict__ vt, u16* __restrict__ ao)
{
    const int nh = blockIdx.x, n = nh >> 3, hh = nh & 7;
    const int q0 = blockIdx.y << 7;
    const int tid = threadIdx.x, wv = tid >> 6, ln = tid & 63;
    const int lq = ln & 31, hi = ln >> 5;

    __shared__ u16 Kl[2][64 * 64];     // [t][d] granule-swizzled
    __shared__ u16 Vl[2][64 * 64];     // [d][t] granule-swizzled + half-swapped

    const u16* Qb = qk + (size_t)n * SD * 1024 + hh * HD;
    const u16* Kb = Qb + 512;
    const u16* Vb = vt + ((size_t)n * 512 + hh * HD) * SD;

    bf16x8 qf[4];
    {
        const u16* qp = Qb + (size_t)(q0 + wv * 32 + lq) * 1024 + hi * 8;
#pragma unroll
        for (int ks = 0; ks < 4; ++ks)
            qf[ks] = *reinterpret_cast<const bf16x8*>(qp + ks * 16);
    }

    f32x16 of0 = {}, of1 = {};         // O^T frags: d 0..31 / 32..63
    float mrun = -INFINITY, lrun = 0.f;

    // staging: 256 threads cover the 64x64 tile in 2 rounds of 16B granules
    const int i0 = tid, i1 = tid + 256;
    const int sr0 = i0 >> 3, g0 = ((i0 & 7) ^ (sr0 & 7)) * 8;
    const int sr1 = i1 >> 3, g1 = ((i1 & 7) ^ (sr1 & 7)) * 8;
    const u16* Ks0 = Kb + (size_t)sr0 * 1024 + g0;
    const u16* Ks1 = Kb + (size_t)sr1 * 1024 + g1;
    const u16* Vs0 = Vb + (size_t)sr0 * SD + g0;
    const u16* Vs1 = Vb + (size_t)sr1 * SD + g1;

    gload16(Ks0, &Kl[0][i0 * 8]);  gload16(Ks1, &Kl[0][i1 * 8]);
    gload16(Vs0, &Vl[0][i0 * 8]);  gload16(Vs1, &Vl[0][i1 * 8]);
    __syncthreads();

    const int hkey = (hi ^ ((lq >> 3) & 1)) * 4;   // V half-swap read key
    int cur = 0;
    for (int tt = 0; tt < 16; ++tt) {
        if (tt < 15) {
            const int t1 = (tt + 1) << 6;
            gload16(Ks0 + (size_t)t1 * 1024, &Kl[cur ^ 1][i0 * 8]);
            gload16(Ks1 + (size_t)t1 * 1024, &Kl[cur ^ 1][i1 * 8]);
            gload16(Vs0 + t1, &Vl[cur ^ 1][i0 * 8]);
            gload16(Vs1 + t1, &Vl[cur ^ 1][i1 * 8]);
        }
        // ---- QK^T: S^T[t][q] (log2 domain; scale folded into Q) ----
        f32x16 st0 = {}, st1 = {};
        const u16* Kc = &Kl[cur][0];
        __builtin_amdgcn_s_setprio(1);
#pragma unroll
        for (int ks = 0; ks < 4; ++ks) {
            const int g = (((ks * 2 + hi) ^ (lq & 7)) * 8);
            bf16x8 k0 = *reinterpret_cast<const bf16x8*>(Kc + lq * 64 + g);
            bf16x8 k1 = *reinterpret_cast<const bf16x8*>(Kc + (32 + lq) * 64 + g);
            st0 = __builtin_amdgcn_mfma_f32_32x32x16_bf16(k0, qf[ks], st0, 0, 0, 0);
            st1 = __builtin_amdgcn_mfma_f32_32x32x16_bf16(k1, qf[ks], st1, 0, 0, 0);
        }
        __builtin_amdgcn_s_setprio(0);
        // ---- online softmax: tree max, defer-max, in-place exp, tree sum ----
        float tm[8];
#pragma unroll
        for (int i = 0; i < 8; ++i)
            tm[i] = fmaxf(fmaxf(st0[i], st0[i + 8]), fmaxf(st1[i], st1[i + 8]));
        float mx = fmaxf(fmaxf(fmaxf(tm[0], tm[1]), fmaxf(tm[2], tm[3])),
                         fmaxf(fmaxf(tm[4], tm[5]), fmaxf(tm[6], tm[7])));
        mx = fmaxf(mx, __shfl_xor(mx, 32));
        if (!__all(mx - mrun <= 8.0f)) {
            const float mn = fmaxf(mrun, mx);
            const float al = exp2v(mrun - mn);   // exp2(-inf)=0 on first tile
            mrun = mn;
            lrun *= al;
#pragma unroll
            for (int r = 0; r < 16; ++r) { of0[r] *= al; of1[r] *= al; }
        }
        float sa = 0.f, sb = 0.f, sc = 0.f, sd = 0.f;
#pragma unroll
        for (int r = 0; r < 16; r += 4) {
            st0[r]     = exp2v(st0[r]     - mrun); sa += st0[r];
            st0[r + 1] = exp2v(st0[r + 1] - mrun); sb += st0[r + 1];
            st0[r + 2] = exp2v(st0[r + 2] - mrun); sc += st0[r + 2];
            st0[r + 3] = exp2v(st0[r + 3] - mrun); sd += st0[r + 3];
        }
#pragma unroll
        for (int r = 0; r < 16; r += 4) {
            st1[r]     = exp2v(st1[r]     - mrun); sa += st1[r];
            st1[r + 1] = exp2v(st1[r + 1] - mrun); sb += st1[r + 1];
            st1[r + 2] = exp2v(st1[r + 2] - mrun); sc += st1[r + 2];
            st1[r + 3] = exp2v(st1[r + 3] - mrun); sd += st1[r + 3];
        }
        float ps = (sa + sb) + (sc + sd);
        ps += __shfl_xor(ps, 32);
        lrun += ps;

        // ---- PV: O^T += V^T · P^T (shared k-slot<->t convention) ----
        const u16* Vc = &Vl[cur][0];
        __builtin_amdgcn_s_setprio(1);
#pragma unroll
        for (int ks = 0; ks < 4; ++ks) {
            union { unsigned w[4]; bf16x8 v; } pf;
            const int rb = (ks & 1) * 8;
            if (ks < 2) {
                pf.w[0] = cvt_pk(st0[rb + 0], st0[rb + 1]);
                pf.w[1] = cvt_pk(st0[rb + 2], st0[rb + 3]);
                pf.w[2] = cvt_pk(st0[rb + 4], st0[rb + 5]);
                pf.w[3] = cvt_pk(st0[rb + 6], st0[rb + 7]);
            } else {
                pf.w[0] = cvt_pk(st1[rb + 0], st1[rb + 1]);
                pf.w[1] = cvt_pk(st1[rb + 2], st1[rb + 3]);
                pf.w[2] = cvt_pk(st1[rb + 4], st1[rb + 5]);
                pf.w[3] = cvt_pk(st1[rb + 6], st1[rb + 7]);
            }
            const int e0 = ((2 * ks) ^ (lq & 7)) * 8 + hkey;
            const int e1 = ((2 * ks + 1) ^ (lq & 7)) * 8 + hkey;
            union { bf16x4 h[2]; bf16x8 v; } vf0, vf1;
            vf0.h[0] = *reinterpret_cast<const bf16x4*>(Vc + lq * 64 + e0);
            vf0.h[1] = *reinterpret_cast<const bf16x4*>(Vc + lq * 64 + e1);
            vf1.h[0] = *reinterpret_cast<const bf16x4*>(Vc + (32 + lq) * 64 + e0);
            vf1.h[1] = *reinterpret_cast<const bf16x4*>(Vc + (32 + lq) * 64 + e1);
            of0 = __builtin_amdgcn_mfma_f32_32x32x16_bf16(vf0.v, pf.v, of0, 0, 0, 0);
            of1 = __builtin_amdgcn_mfma_f32_32x32x16_bf16(vf1.v, pf.v, of1, 0, 0, 0);
        }
        __builtin_amdgcn_s_setprio(0);
        __syncthreads();
        cur ^= 1;
    }

    const float inv = 1.0f / lrun;
    u16* op = ao + ((size_t)n * SD + q0 + wv * 32 + lq) * CD + hh * HD;
#pragma unroll
    for (int g = 0; g < 4; ++g) {
        u16x4 o0, o1;
#pragma unroll
        for (int e = 0; e < 4; ++e) {
            o0[e] = f2bf(of0[g * 4 + e] * inv);
            o1[e] = f2bf(of1[g * 4 + e] * inv);
        }
        const int d0 = g * 8 + hi * 4;
        *reinterpret_cast<u16x4*>(op + d0) = o0;
        *reinterpret_cast<u16x4*>(op + 32 + d0) = o1;
    }
}

// ---------------------------------------------------------------------------
extern "C" void kernel_launch(void* const* d_in, const int* in_sizes, int n_in,
                              void* d_out, int out_size, void* d_ws, size_t ws_size,
                              hipStream_t stream)
{
    const float* x      = (const float*)d_in[0];
    const float* norm_w = (const float*)d_in[1];
    const float* norm_b = (const float*)d_in[2];
    const float* qkv_w  = (const float*)d_in[3];
    const float* qkv_b  = (const float*)d_in[4];
    const float* proj_w = (const float*)d_in[5];
    const float* proj_b = (const float*)d_in[6];

    // ws (u16 elems): h | qk | vt | ao | wq | wp   (~86 MiB)
    u16* h   = (u16*)d_ws;                        // [16][1024][512]
    u16* qkb = h + (size_t)NB * SD * CD;          // [16][1024][1024]  (Q|K)
    u16* vtb = qkb + (size_t)NB * SD * 1024;      // [16][512][1024]   (V^T, half-swapped)
    u16* ao  = vtb + (size_t)NB * 512 * SD;       // [16][1024][512]
    u16* wq  = ao + (size_t)NB * SD * CD;         // [1536][512]
    u16* wp  = wq + (size_t)1536 * CD;            // [512][512]

    hipLaunchKernelGGL(cvt2_kernel, dim3(1024), dim3(256), 0, stream,
                       qkv_w, wq, proj_w, wp);
    hipLaunchKernelGGL(gn_kernel, dim3(NB * 32), dim3(256), 0, stream, x, norm_w, norm_b, h);
    hipLaunchKernelGGL((mfma_gemm<0>), dim3(8, 12, NB), dim3(256), 0, stream,
                       wq, h, qkv_b, (const float*)nullptr, (void*)qkb, vtb, 1536);
    hipLaunchKernelGGL(attn_mfma, dim3(NB * NH, SD / 128), dim3(256), 0, stream,
                       qkb, vtb, ao);
    hipLaunchKernelGGL((mfma_gemm<1>), dim3(8, 4, NB), dim3(256), 0, stream,
                       wp, ao, proj_b, x, (void*)d_out, (u16*)nullptr, 512);
}

// Round 9
// 217.654 us; speedup vs baseline: 1.1420x; 1.1420x over previous
//
#include <hip/hip_runtime.h>
#include <cstdint>
#include <cstddef>

typedef unsigned short u16;
typedef __attribute__((ext_vector_type(8))) short bf16x8;   // 8 bf16 = 4 VGPR
typedef __attribute__((ext_vector_type(4))) short bf16x4;   // 4 bf16 = 2 VGPR
typedef __attribute__((ext_vector_type(4))) float f32x4;
typedef __attribute__((ext_vector_type(16))) float f32x16;
typedef __attribute__((ext_vector_type(4))) unsigned short u16x4;

#define NB 16
#define CD 512
#define SD 1024
#define NH 8
#define HD 64

// 0.125 (1/sqrt(64)) * log2(e): folded into Q so softmax runs in log2 domain
#define QSCL 0.18033688011112042f

__device__ __forceinline__ u16 f2bf(float f) {          // round-to-nearest-even
    unsigned u = __float_as_uint(f);
    u += 0x7FFF + ((u >> 16) & 1);
    return (u16)(u >> 16);
}
__device__ __forceinline__ unsigned cvt_pk(float lo, float hi) {
    unsigned r;
    asm("v_cvt_pk_bf16_f32 %0, %1, %2" : "=v"(r) : "v"(lo), "v"(hi));
    return r;
}
__device__ __forceinline__ float exp2v(float x) {       // 2^x, single v_exp_f32
    float r;
    asm("v_exp_f32 %0, %1" : "=v"(r) : "v"(x));
    return r;
}
__device__ __forceinline__ void gload16(const void* g, void* l) {
    __builtin_amdgcn_global_load_lds(
        (const __attribute__((address_space(1))) void*)g,
        (__attribute__((address_space(3))) void*)l, 16, 0, 0);
}

// ---------------------------------------------------------------------------
// fp32 -> bf16 weight convert (both weight tensors in one launch)
// ---------------------------------------------------------------------------
__global__ __launch_bounds__(256) void cvt2_kernel(
    const float* __restrict__ s0, u16* __restrict__ d0,
    const float* __restrict__ s1, u16* __restrict__ d1)
{
    const int bid = blockIdx.x;
    const float* s;
    u16* d;
    int i;
    if (bid < 768) { s = s0; d = d0; i = (bid * 256 + threadIdx.x) * 4; }
    else           { s = s1; d = d1; i = ((bid - 768) * 256 + threadIdx.x) * 4; }
    float4 v = *reinterpret_cast<const float4*>(s + i);
    u16x4 o = { f2bf(v.x), f2bf(v.y), f2bf(v.z), f2bf(v.w) };
    *reinterpret_cast<u16x4*>(d + i) = o;
}

// ---------------------------------------------------------------------------
// GroupNorm: x [n][c][s] fp32 -> h [n][s][c] bf16
// ---------------------------------------------------------------------------
__global__ __launch_bounds__(256) void gn_kernel(
    const float* __restrict__ x, const float* __restrict__ w,
    const float* __restrict__ b, u16* __restrict__ h)
{
    const int n = blockIdx.x >> 5, g = blockIdx.x & 31;
    const size_t base = ((size_t)n * CD + g * 16) * SD;
    const float4* xp = reinterpret_cast<const float4*>(x + base);

    float4 vals[16];
    float sum = 0.f, ss = 0.f;
#pragma unroll
    for (int i = 0; i < 16; ++i) {
        float4 v = xp[threadIdx.x + (i << 8)];
        vals[i] = v;
        sum += v.x + v.y + v.z + v.w;
        ss  += v.x*v.x + v.y*v.y + v.z*v.z + v.w*v.w;
    }
#pragma unroll
    for (int off = 32; off > 0; off >>= 1) {
        sum += __shfl_down(sum, off);
        ss  += __shfl_down(ss,  off);
    }
    __shared__ float rs[4], rq[4];
    const int wid = threadIdx.x >> 6, lane = threadIdx.x & 63;
    if (lane == 0) { rs[wid] = sum; rq[wid] = ss; }
    __syncthreads();
    const float tsum = rs[0] + rs[1] + rs[2] + rs[3];
    const float tss  = rq[0] + rq[1] + rq[2] + rq[3];
    const float mean = tsum * (1.0f / 16384.0f);
    const float var  = tss * (1.0f / 16384.0f) - mean * mean;
    const float inv  = rsqrtf(var + 1e-5f);

    u16* hp = h + ((size_t)n * SD + 4 * threadIdx.x) * CD + g * 16;
#pragma unroll
    for (int i = 0; i < 16; ++i) {
        const float A  = inv * w[g * 16 + i];
        const float Bc = b[g * 16 + i] - mean * A;
        float4 v = vals[i];
        hp[i]          = f2bf(v.x * A + Bc);
        hp[CD + i]     = f2bf(v.y * A + Bc);
        hp[2 * CD + i] = f2bf(v.z * A + Bc);
        hp[3 * CD + i] = f2bf(v.w * A + Bc);
    }
}

// ---------------------------------------------------------------------------
// MFMA GEMM, K = 512. Tile 128x128, BK=64, 4 waves, 16x16x32 MFMA,
// XOR-granule swizzled LDS via global_load_lds. Template MODE (R4 lesson).
// __launch_bounds__(256,4): pin VGPR <= 128 -> 4 waves/SIMD (R8 lesson:
// epilogue addressing pushed 128->132 and cost 25% occupancy).
// MODE 0: m<512 scaled by QSCL -> qk; m>=1024 -> V half-swapped granules
//   (s^4 for d-rows with bit3 set; XOR hoisted into base ptr so all store
//   offsets are immediates: (a^4)+16*nj == (a+16*nj)^4, bit2 never carries).
// MODE 1: D^T + bias + resid, float4 stores.
// ---------------------------------------------------------------------------
template<int MODE>
__global__ __launch_bounds__(256, 4) void mfma_gemm(
    const u16* __restrict__ Wb, const u16* __restrict__ act,
    const float* __restrict__ bias, const float* __restrict__ resid,
    void* __restrict__ outp, u16* __restrict__ vtout, int M)
{
    const int nb = blockIdx.z, m0 = blockIdx.y * 128, s0 = blockIdx.x * 128;
    __shared__ u16 Al[128 * 64];
    __shared__ u16 Bl[128 * 64];
    const int tid = threadIdx.x, wv = tid >> 6, ln = tid & 63;
    const int wm = wv >> 1, wn = wv & 1, lr = ln & 15, lg = ln >> 4;

    const f32x4 zero = {0.f, 0.f, 0.f, 0.f};
    f32x4 acc[4][4];
#pragma unroll
    for (int i = 0; i < 4; ++i)
#pragma unroll
        for (int j = 0; j < 4; ++j) acc[i][j] = zero;

    const u16* Ab = Wb + (size_t)m0 * CD;
    const u16* Bb = act + ((size_t)nb * SD + s0) * CD;

    for (int k0 = 0; k0 < CD; k0 += 64) {
        __syncthreads();
#pragma unroll
        for (int r = 0; r < 4; ++r) {
            const int gi = (r * 4 + wv) * 64 + ln;
            const int row = gi >> 3, gc = gi & 7;
            const int sg = ((gc ^ (row & 7)) * 8);
            gload16(Ab + (size_t)row * CD + k0 + sg, Al + gi * 8);
            gload16(Bb + (size_t)row * CD + k0 + sg, Bl + gi * 8);
        }
        __syncthreads();

#pragma unroll
        for (int kc = 0; kc < 2; ++kc) {
            bf16x8 af[4], bfr[4];
#pragma unroll
            for (int mi = 0; mi < 4; ++mi) {
                const int row = wm * 64 + mi * 16 + lr;
                af[mi] = *reinterpret_cast<const bf16x8*>(
                    Al + row * 64 + (((kc * 4 + lg) ^ (row & 7)) * 8));
            }
#pragma unroll
            for (int nj = 0; nj < 4; ++nj) {
                const int row = wn * 64 + nj * 16 + lr;
                bfr[nj] = *reinterpret_cast<const bf16x8*>(
                    Bl + row * 64 + (((kc * 4 + lg) ^ (row & 7)) * 8));
            }
#pragma unroll
            for (int mi = 0; mi < 4; ++mi)
#pragma unroll
                for (int nj = 0; nj < 4; ++nj) {
                    if (MODE == 0)
                        acc[mi][nj] = __builtin_amdgcn_mfma_f32_16x16x32_bf16(
                            af[mi], bfr[nj], acc[mi][nj], 0, 0, 0);
                    else   // D^T: A = act rows (s), B = weight rows (m)
                        acc[mi][nj] = __builtin_amdgcn_mfma_f32_16x16x32_bf16(
                            bfr[mi], af[nj], acc[mi][nj], 0, 0, 0);
                }
        }
    }

    if (MODE == 0) {
        if (m0 < 1024) {                                     // Q|K -> qk[n][s][1024]
            u16* o = (u16*)outp;
            const float sc = (m0 < 512) ? QSCL : 1.0f;       // whole block uniform
#pragma unroll
            for (int mi = 0; mi < 4; ++mi) {
                const int mb = m0 + wm * 64 + mi * 16 + lg * 4;
#pragma unroll
                for (int nj = 0; nj < 4; ++nj) {
                    const int s = s0 + wn * 64 + nj * 16 + lr;
                    u16x4 pack;
#pragma unroll
                    for (int r = 0; r < 4; ++r)
                        pack[r] = f2bf((acc[mi][nj][r] + bias[mb + r]) * sc);
                    *reinterpret_cast<u16x4*>(o + ((size_t)nb * SD + s) * 1024 + mb) = pack;
                }
            }
        } else {                                             // V -> vt[(n*512+c)][s]
            // half-swap granules for d-rows with bit3 set (lg>=2); XOR hoisted
            // into the base pointer so all 64 store offsets are immediates.
            const int sswap = (lg >= 2) ? 4 : 0;
            const int sbase = (s0 + wn * 64 + lr) ^ sswap;
            const int mb = m0 - 1024 + wm * 64 + lg * 4;
            u16* vb = vtout + ((size_t)nb * 512 + mb) * SD + sbase;
            const float* bp = bias + m0 + wm * 64 + lg * 4;
#pragma unroll
            for (int mi = 0; mi < 4; ++mi)
#pragma unroll
                for (int r = 0; r < 4; ++r) {
                    const float bi = bp[mi * 16 + r];
#pragma unroll
                    for (int nj = 0; nj < 4; ++nj)
                        vb[(size_t)(mi * 16 + r) * SD + nj * 16] =
                            f2bf(acc[mi][nj][r] + bi);
                }
        }
    } else {
        // D^T epilogue: acc[i][j] rows = s (i-frags), cols = m (j-frags)
        float* o = (float*)outp;
#pragma unroll
        for (int i = 0; i < 4; ++i)
#pragma unroll
            for (int j = 0; j < 4; ++j) {
                const int m = m0 + wm * 64 + j * 16 + lr;
                const int s = s0 + wn * 64 + i * 16 + lg * 4;
                const float bi = bias[m];
                const size_t idx = ((size_t)nb * M + m) * SD + s;
                float4 r4 = *reinterpret_cast<const float4*>(resid + idx);
                float4 v;
                v.x = acc[i][j][0] + bi + r4.x;
                v.y = acc[i][j][1] + bi + r4.y;
                v.z = acc[i][j][2] + bi + r4.z;
                v.w = acc[i][j][3] + bi + r4.w;
                *reinterpret_cast<float4*>(o + idx) = v;
            }
    }
}

// ---------------------------------------------------------------------------
// Flash attention — R7 structure (512 thr, QBLK=256, 8 waves, measured 57 µs)
// + isolated bank-conflict fix: V stored half-swapped (gemm epilogue), read
// with hkey = (hi ^ (lq>>3 & 1))*4 so each 16-lane b64 service group covers
// all 32 banks (was 16). Tree max / in-place exp kept from R8 (VGPR diet).
// ---------------------------------------------------------------------------
__global__ __launch_bounds__(512) void attn_mfma(
    const u16* __restrict__ qk, const u16* __restrict__ vt, u16* __restrict__ ao)
{
    const int nh = blockIdx.y, n = nh >> 3, hh = nh & 7;
    const int q0 = blockIdx.x << 8;
    const int tid = threadIdx.x, wv = tid >> 6, ln = tid & 63;
    const int lq = ln & 31, hi = ln >> 5;

    __shared__ u16 Kl[2][64 * 64];     // [t][d] granule-swizzled
    __shared__ u16 Vl[2][64 * 64];     // [d][t] granule-swizzled + half-swapped

    const u16* Qb = qk + (size_t)n * SD * 1024 + hh * HD;
    const u16* Kb = Qb + 512;
    const u16* Vb = vt + ((size_t)n * 512 + hh * HD) * SD;

    bf16x8 qf[4];
    {
        const u16* qp = Qb + (size_t)(q0 + wv * 32 + lq) * 1024 + hi * 8;
#pragma unroll
        for (int ks = 0; ks < 4; ++ks)
            qf[ks] = *reinterpret_cast<const bf16x8*>(qp + ks * 16);
    }

    f32x16 of0 = {}, of1 = {};         // O^T frags: d 0..31 / 32..63
    float mrun = -INFINITY, lrun = 0.f;

    const int srow = tid >> 3, sgc = tid & 7;
    const int ssw = (sgc ^ (srow & 7)) * 8;
    const u16* Ksrc = Kb + (size_t)srow * 1024 + ssw;
    const u16* Vsrc = Vb + (size_t)srow * SD + ssw;

    gload16(Ksrc, &Kl[0][tid * 8]);
    gload16(Vsrc, &Vl[0][tid * 8]);
    __syncthreads();

    const int hkey = (hi ^ ((lq >> 3) & 1)) * 4;   // V half-swap read key
    int cur = 0;
    for (int tt = 0; tt < 16; ++tt) {
        if (tt < 15) {
            const int t1 = (tt + 1) << 6;
            gload16(Ksrc + (size_t)t1 * 1024, &Kl[cur ^ 1][tid * 8]);
            gload16(Vsrc + t1, &Vl[cur ^ 1][tid * 8]);
        }
        // ---- QK^T: S^T[t][q] (log2 domain; scale folded into Q) ----
        f32x16 st0 = {}, st1 = {};
        const u16* Kc = &Kl[cur][0];
        __builtin_amdgcn_s_setprio(1);
#pragma unroll
        for (int ks = 0; ks < 4; ++ks) {
            const int g = (((ks * 2 + hi) ^ (lq & 7)) * 8);
            bf16x8 k0 = *reinterpret_cast<const bf16x8*>(Kc + lq * 64 + g);
            bf16x8 k1 = *reinterpret_cast<const bf16x8*>(Kc + (32 + lq) * 64 + g);
            st0 = __builtin_amdgcn_mfma_f32_32x32x16_bf16(k0, qf[ks], st0, 0, 0, 0);
            st1 = __builtin_amdgcn_mfma_f32_32x32x16_bf16(k1, qf[ks], st1, 0, 0, 0);
        }
        __builtin_amdgcn_s_setprio(0);
        // ---- online softmax: tree max, defer-max, in-place exp, tree sum ----
        float tm[8];
#pragma unroll
        for (int i = 0; i < 8; ++i)
            tm[i] = fmaxf(fmaxf(st0[i], st0[i + 8]), fmaxf(st1[i], st1[i + 8]));
        float mx = fmaxf(fmaxf(fmaxf(tm[0], tm[1]), fmaxf(tm[2], tm[3])),
                         fmaxf(fmaxf(tm[4], tm[5]), fmaxf(tm[6], tm[7])));
        mx = fmaxf(mx, __shfl_xor(mx, 32));
        if (!__all(mx - mrun <= 8.0f)) {
            const float mn = fmaxf(mrun, mx);
            const float al = exp2v(mrun - mn);   // exp2(-inf)=0 on first tile
            mrun = mn;
            lrun *= al;
#pragma unroll
            for (int r = 0; r < 16; ++r) { of0[r] *= al; of1[r] *= al; }
        }
        float sa = 0.f, sb = 0.f, sc = 0.f, sd = 0.f;
#pragma unroll
        for (int r = 0; r < 16; r += 4) {
            st0[r]     = exp2v(st0[r]     - mrun); sa += st0[r];
            st0[r + 1] = exp2v(st0[r + 1] - mrun); sb += st0[r + 1];
            st0[r + 2] = exp2v(st0[r + 2] - mrun); sc += st0[r + 2];
            st0[r + 3] = exp2v(st0[r + 3] - mrun); sd += st0[r + 3];
        }
#pragma unroll
        for (int r = 0; r < 16; r += 4) {
            st1[r]     = exp2v(st1[r]     - mrun); sa += st1[r];
            st1[r + 1] = exp2v(st1[r + 1] - mrun); sb += st1[r + 1];
            st1[r + 2] = exp2v(st1[r + 2] - mrun); sc += st1[r + 2];
            st1[r + 3] = exp2v(st1[r + 3] - mrun); sd += st1[r + 3];
        }
        float ps = (sa + sb) + (sc + sd);
        ps += __shfl_xor(ps, 32);
        lrun += ps;

        // ---- PV: O^T += V^T · P^T (shared k-slot<->t convention) ----
        const u16* Vc = &Vl[cur][0];
        __builtin_amdgcn_s_setprio(1);
#pragma unroll
        for (int ks = 0; ks < 4; ++ks) {
            union { unsigned w[4]; bf16x8 v; } pf;
            const int rb = (ks & 1) * 8;
            if (ks < 2) {
                pf.w[0] = cvt_pk(st0[rb + 0], st0[rb + 1]);
                pf.w[1] = cvt_pk(st0[rb + 2], st0[rb + 3]);
                pf.w[2] = cvt_pk(st0[rb + 4], st0[rb + 5]);
                pf.w[3] = cvt_pk(st0[rb + 6], st0[rb + 7]);
            } else {
                pf.w[0] = cvt_pk(st1[rb + 0], st1[rb + 1]);
                pf.w[1] = cvt_pk(st1[rb + 2], st1[rb + 3]);
                pf.w[2] = cvt_pk(st1[rb + 4], st1[rb + 5]);
                pf.w[3] = cvt_pk(st1[rb + 6], st1[rb + 7]);
            }
            const int e0 = ((2 * ks) ^ (lq & 7)) * 8 + hkey;
            const int e1 = ((2 * ks + 1) ^ (lq & 7)) * 8 + hkey;
            union { bf16x4 h[2]; bf16x8 v; } vf0, vf1;
            vf0.h[0] = *reinterpret_cast<const bf16x4*>(Vc + lq * 64 + e0);
            vf0.h[1] = *reinterpret_cast<const bf16x4*>(Vc + lq * 64 + e1);
            vf1.h[0] = *reinterpret_cast<const bf16x4*>(Vc + (32 + lq) * 64 + e0);
            vf1.h[1] = *reinterpret_cast<const bf16x4*>(Vc + (32 + lq) * 64 + e1);
            of0 = __builtin_amdgcn_mfma_f32_32x32x16_bf16(vf0.v, pf.v, of0, 0, 0, 0);
            of1 = __builtin_amdgcn_mfma_f32_32x32x16_bf16(vf1.v, pf.v, of1, 0, 0, 0);
        }
        __builtin_amdgcn_s_setprio(0);
        __syncthreads();
        cur ^= 1;
    }

    const float inv = 1.0f / lrun;
    u16* op = ao + ((size_t)n * SD + q0 + wv * 32 + lq) * CD + hh * HD;
#pragma unroll
    for (int g = 0; g < 4; ++g) {
        u16x4 o0, o1;
#pragma unroll
        for (int e = 0; e < 4; ++e) {
            o0[e] = f2bf(of0[g * 4 + e] * inv);
            o1[e] = f2bf(of1[g * 4 + e] * inv);
        }
        const int d0 = g * 8 + hi * 4;
        *reinterpret_cast<u16x4*>(op + d0) = o0;
        *reinterpret_cast<u16x4*>(op + 32 + d0) = o1;
    }
}

// ---------------------------------------------------------------------------
extern "C" void kernel_launch(void* const* d_in, const int* in_sizes, int n_in,
                              void* d_out, int out_size, void* d_ws, size_t ws_size,
                              hipStream_t stream)
{
    const float* x      = (const float*)d_in[0];
    const float* norm_w = (const float*)d_in[1];
    const float* norm_b = (const float*)d_in[2];
    const float* qkv_w  = (const float*)d_in[3];
    const float* qkv_b  = (const float*)d_in[4];
    const float* proj_w = (const float*)d_in[5];
    const float* proj_b = (const float*)d_in[6];

    // ws (u16 elems): h | qk | vt | ao | wq | wp   (~86 MiB)
    u16* h   = (u16*)d_ws;                        // [16][1024][512]
    u16* qkb = h + (size_t)NB * SD * CD;          // [16][1024][1024]  (Q|K)
    u16* vtb = qkb + (size_t)NB * SD * 1024;      // [16][512][1024]   (V^T, half-swapped)
    u16* ao  = vtb + (size_t)NB * 512 * SD;       // [16][1024][512]
    u16* wq  = ao + (size_t)NB * SD * CD;         // [1536][512]
    u16* wp  = wq + (size_t)1536 * CD;            // [512][512]

    hipLaunchKernelGGL(cvt2_kernel, dim3(1024), dim3(256), 0, stream,
                       qkv_w, wq, proj_w, wp);
    hipLaunchKernelGGL(gn_kernel, dim3(NB * 32), dim3(256), 0, stream, x, norm_w, norm_b, h);
    hipLaunchKernelGGL((mfma_gemm<0>), dim3(8, 12, NB), dim3(256), 0, stream,
                       wq, h, qkv_b, (const float*)nullptr, (void*)qkb, vtb, 1536);
    hipLaunchKernelGGL(attn_mfma, dim3(SD / 256, NB * NH), dim3(512), 0, stream,
                       qkb, vtb, ao);
    hipLaunchKernelGGL((mfma_gemm<1>), dim3(8, 4, NB), dim3(256), 0, stream,
                       wp, ao, proj_b, x, (void*)d_out, (u16*)nullptr, 512);
}